// Round 8
// baseline (77.032 us; speedup 1.0000x reference)
//
#include <hip/hip_runtime.h>

// SpikeFP32LookupExp2: out[pos, :] = table_bits[j(pos), :] where
// j(pos) = sum_k (idx_bits[pos,k] > 0.5) << k.  Pure row-gather, memory-bound
// (~310 MB irreducible, 87% write; ceilings: copy 6.29 TB/s, fill 7.0 TB/s).
//
// Round 8: TWO-KERNEL global phase split (R7's per-wave split can't separate
// the streams -- waves desync; this does it at dispatch granularity):
//   Kernel A (read phase): 40 MB idx reads -> 2 MB packed j bytes in d_ws.
//   Kernel B (write phase): 2 MB j re-read (L2-resident) + 268 MB nt-store
//     stream -> ~99% write, should approach the 7.0 TB/s fill rate instead
//     of the 6.29 TB/s mixed-copy rate.
// Fallback to the proven 51.6 us single-pass if ws_size < n_pos bytes.

typedef float floatx4 __attribute__((ext_vector_type(4)));

// ---- Kernel A: resolve j for all positions, write 1 byte each ----------
__global__ __launch_bounds__(256) void spike_jidx_kernel(
    const float* __restrict__ idx_bits,  // [n_pos * 5]
    unsigned char* __restrict__ jout,    // [n_pos]
    long n_pos) {
  const long total = n_pos * 8;  // 8 lanes per position (ballot groups)
  const long nthreads = (long)gridDim.x * blockDim.x;
  const long gid = (long)blockIdx.x * blockDim.x + threadIdx.x;
  const int lane8 = (int)(gid & 7);
  const int bit_lane = lane8 < 5 ? lane8 : 4;  // branchless clamped load
  const unsigned shift = threadIdx.x & 56;

#pragma unroll 4
  for (long g = gid; g < total; g += nthreads) {
    const long pos = g >> 3;
    const float v = idx_bits[pos * 5 + bit_lane];
    const unsigned long long m = __ballot(v > 0.5f);
    const unsigned j = (unsigned)((m >> shift) & 31ull);
    if (lane8 == 0) jout[pos] = (unsigned char)j;  // 8 consecutive bytes/wave
  }
}

// ---- Kernel B: near-pure write stream -----------------------------------
__global__ __launch_bounds__(256) void spike_write_kernel(
    const unsigned char* __restrict__ jin,  // [n_pos]
    const float* __restrict__ table_bits,   // [32 * 32]
    float* __restrict__ out,                // [n_pos * 32]
    long n_pos) {
  const long total4 = n_pos * 8;  // float4 outputs
  const long nthreads = (long)gridDim.x * blockDim.x;
  const long gid = (long)blockIdx.x * blockDim.x + threadIdx.x;
  const int lane8 = (int)(gid & 7);

#pragma unroll 4
  for (long g = gid; g < total4; g += nthreads) {
    const long pos = g >> 3;
    const unsigned j = jin[pos];  // L2-resident, 8-way lane broadcast
    const floatx4 row = *reinterpret_cast<const floatx4*>(
        table_bits + (j << 5) + (lane8 << 2));  // 4 KB table, L1-resident
    __builtin_nontemporal_store(row,
                                reinterpret_cast<floatx4*>(out + (g << 2)));
  }
}

// ---- Fallback: proven single-pass (R3 structure, 51.6 us) ---------------
__global__ __launch_bounds__(256) void spike_lookup_kernel(
    const float* __restrict__ idx_bits, const float* __restrict__ table_bits,
    float* __restrict__ out, long n_pos) {
  const long total4 = n_pos * 8;
  const long nthreads = (long)gridDim.x * blockDim.x;
  const long gid = (long)blockIdx.x * blockDim.x + threadIdx.x;
  const int lane8 = (int)(gid & 7);
  const int bit_lane = lane8 < 5 ? lane8 : 4;
  const unsigned shift = threadIdx.x & 56;
#pragma unroll 4
  for (long g = gid; g < total4; g += nthreads) {
    const long pos = g >> 3;
    const float v = idx_bits[pos * 5 + bit_lane];
    const unsigned long long m = __ballot(v > 0.5f);
    const unsigned j = (unsigned)((m >> shift) & 31ull);
    const floatx4 row = *reinterpret_cast<const floatx4*>(
        table_bits + (j << 5) + (lane8 << 2));
    __builtin_nontemporal_store(row,
                                reinterpret_cast<floatx4*>(out + (g << 2)));
  }
}

extern "C" void kernel_launch(void* const* d_in, const int* in_sizes, int n_in,
                              void* d_out, int out_size, void* d_ws, size_t ws_size,
                              hipStream_t stream) {
  const float* idx_bits = (const float*)d_in[0];    // (1024, 2048, 5) f32
  const float* table_bits = (const float*)d_in[1];  // (32, 32) f32
  float* out = (float*)d_out;                       // (1024, 2048, 32) f32

  const long n_pos = in_sizes[0] / 5;  // 2,097,152
  const int block = 256;
  const int grid = 4096;  // 32 waves/CU resident, grid-stride

  if (ws_size >= (size_t)n_pos) {
    unsigned char* jbuf = (unsigned char*)d_ws;
    spike_jidx_kernel<<<grid, block, 0, stream>>>(idx_bits, jbuf, n_pos);
    spike_write_kernel<<<grid, block, 0, stream>>>(jbuf, table_bits, out,
                                                   n_pos);
  } else {
    spike_lookup_kernel<<<grid, block, 0, stream>>>(idx_bits, table_bits, out,
                                                    n_pos);
  }
}

// Round 9
// 52.297 us; speedup vs baseline: 1.4730x; 1.4730x over previous
//
#include <hip/hip_runtime.h>

// SpikeFP32LookupExp2: out[pos, :] = table_bits[j(pos), :] where
// j(pos) = sum_k (idx_bits[pos,k] > 0.5) << k.  Pure row-gather, memory-bound.
//
// FINAL (revert to proven best = R3 structure, 51.6 us, 3 consistent repeats):
//  - ~308 MB irreducible traffic (40 MB read + 268 MB write); 51.6 us =
//    5.97 TB/s effective = 95% of the measured mixed-stream ceiling
//    (6.29 TB/s copy, m13).  Phase-separation attempts (R7 in-kernel,
//    R8 two-kernel) both regressed -> mixed-stream rate IS the wall here.
//  - 8 lanes per position; each lane stores one float4 of the 128 B row
//    (1 KB fully-coalesced wave stores).
//  - Branchless ballot-j: every lane loads idx_bits[pos*5 + min(lane8,4)]
//    (one coalesced dword load per wave covers 8 positions; group bits 5-7
//    of the ballot are discarded by &31).
//  - Grid-stride, 16 iters/thread, unroll 4: 4 independent chains in flight
//    per wave (this is what took 80 us -> 51.6 us; unroll 8 was neutral).
//  - Nontemporal float4 stores (write-once stream; HIP float4 is a struct,
//    the builtin needs an ext_vector_type).

typedef float floatx4 __attribute__((ext_vector_type(4)));

__global__ __launch_bounds__(256) void spike_lookup_kernel(
    const float* __restrict__ idx_bits,   // [n_pos * 5]
    const float* __restrict__ table_bits, // [32 * 32]
    float* __restrict__ out,              // [n_pos * 32]
    long n_pos) {
  const long total4 = n_pos * 8;  // total float4 outputs
  const long nthreads = (long)gridDim.x * blockDim.x;
  const long gid = (long)blockIdx.x * blockDim.x + threadIdx.x;
  const int lane8 = (int)(gid & 7);              // which float4 of the row
  const int bit_lane = lane8 < 5 ? lane8 : 4;    // clamped: branchless load
  const unsigned shift = threadIdx.x & 56;       // group base within the wave

#pragma unroll 4
  for (long g = gid; g < total4; g += nthreads) {
    const long pos = g >> 3;
    const float v = idx_bits[pos * 5 + bit_lane];  // unconditional, coalesced
    const unsigned long long m = __ballot(v > 0.5f);
    const unsigned j = (unsigned)((m >> shift) & 31ull);  // bits 5-7 masked

    const floatx4 row = *reinterpret_cast<const floatx4*>(
        table_bits + (j << 5) + (lane8 << 2));     // 4 KB table, L1-resident

    __builtin_nontemporal_store(row,
                                reinterpret_cast<floatx4*>(out + (g << 2)));
  }
}

extern "C" void kernel_launch(void* const* d_in, const int* in_sizes, int n_in,
                              void* d_out, int out_size, void* d_ws, size_t ws_size,
                              hipStream_t stream) {
  const float* idx_bits = (const float*)d_in[0];    // (1024, 2048, 5) f32
  const float* table_bits = (const float*)d_in[1];  // (32, 32) f32
  float* out = (float*)d_out;                       // (1024, 2048, 32) f32

  const long n_pos = in_sizes[0] / 5;  // 2,097,152
  const int block = 256;
  const int grid = 4096;  // 16 float4s per thread, 32 waves/CU resident

  spike_lookup_kernel<<<grid, block, 0, stream>>>(idx_bits, table_bits, out,
                                                  n_pos);
}